// Round 6
// baseline (560.963 us; speedup 1.0000x reference)
//
#include <hip/hip_runtime.h>

// VectorQuantizer: z (8,64,8192) f32, codebook (1024,64) f32
// Outputs (concatenated f32): z_q_st [4194304], vq_loss [1], codes [65536]
//
// codes must match numpy fp32 argmin BIT-EXACTLY -> replicate numpy op order:
//   zsq/wsq: pairwise_sum n=64 (8 serial column accumulators, rounded squares)
//   dot:     single serial FMA chain over k ascending (BLAS sgemm order)
//   dist:    fl(fl(zsq - fl(2*dot)) + wsq), argmin = first occurrence of min.
//
// R3-R8: every z-in-registers variant is frozen at dist=190us, VGPR=40
//   (regalloc homes z in AGPRs). R9: z staged in LDS column-major
//   (ds_read_b128 conflict-free), VGPR=88, AGPR shuttle gone -- dist STILL
//   192us, VALUBusy STILL 64%, FETCH STILL 9.27MB. z-delivery was never the
//   bottleneck. The invariant across all rounds is W-DELIVERY: wave-uniform
//   wp[k] -> scalar s_loads, SGPR-budget-chunked (~112 SGPRs), each chunk
//   gated by lgkmcnt with ~L2 latency (64KiB segment >> K$), only 2-2.65
//   waves/SIMD to cover -> ~35% idle. Occupancy-insensitive (33%->20% same
//   dur) because the stall is per-chunk serialization on a shared path.
// R10: force w onto the VECTOR memory path. asm "+v" on the codebook POINTER
//   makes it a VGPR address -> compiler must emit per-lane
//   global_load_dwordx4 (uniform addr -> L1/L2 broadcast). vmcnt queue is
//   64-deep per wave vs ~4-8 chunked s_loads -> latency gets pipelined.
//   Explicit float4 reads; imm offsets cover each 8-code group.
//   Chain order unchanged -> bit-exact.
// R11 (this round): R10 never ran -- macro parameter named `w` clobbered the
//   member access `zk.w` (token substitution) -> compile error. Renamed to
//   `wv`. Same kernel, same theory, same predictions:
//   Predict: dist 192 -> 75-120us; VGPR 88 -> 110-170; VALUBusy >= 75%.
//   Falsifier: dur unchanged -> w-path was fine; next = GEMM-transpose
//   layout (lanes own codes, z uniform, cross-lane first-min argmin).

#define T_DIM 8192
#define D_DIM 64
#define C_DIM 1024
#define B_DIM 8
#define NROWS (B_DIM * T_DIM)           // 65536 vectors
#define NELEM (B_DIM * D_DIM * T_DIM)   // 4194304 elements
#define SEGS 4
#define CODES_PER_SEG (C_DIM / SEGS)    // 256
#define EPI_BLOCKS (NELEM / 4 / 256)    // 4096 blocks, 1 float4/thread

#define R64(M) M(0) M(1) M(2) M(3) M(4) M(5) M(6) M(7) \
  M(8) M(9) M(10) M(11) M(12) M(13) M(14) M(15) \
  M(16) M(17) M(18) M(19) M(20) M(21) M(22) M(23) \
  M(24) M(25) M(26) M(27) M(28) M(29) M(30) M(31) \
  M(32) M(33) M(34) M(35) M(36) M(37) M(38) M(39) \
  M(40) M(41) M(42) M(43) M(44) M(45) M(46) M(47) \
  M(48) M(49) M(50) M(51) M(52) M(53) M(54) M(55) \
  M(56) M(57) M(58) M(59) M(60) M(61) M(62) M(63)

#define SQ_(x) __fmul_rn(x, x)
#define AD_(a, b) __fadd_rn(a, b)

// numpy pairwise_sum of 64 pre-rounded squares of scalars p0..p63 -> dst.
// Column j accumulates p{j}, p{j+8}, ..., p{j+56} serially; columns combined
// ((r0+r1)+(r2+r3)) + ((r4+r5)+(r6+r7)). All ops individually rounded.
#define PAIRWISE64(p, dst) \
  float pr0 = SQ_(p##0);  pr0 = AD_(pr0, SQ_(p##8));  pr0 = AD_(pr0, SQ_(p##16)); pr0 = AD_(pr0, SQ_(p##24)); pr0 = AD_(pr0, SQ_(p##32)); pr0 = AD_(pr0, SQ_(p##40)); pr0 = AD_(pr0, SQ_(p##48)); pr0 = AD_(pr0, SQ_(p##56)); \
  float pr1 = SQ_(p##1);  pr1 = AD_(pr1, SQ_(p##9));  pr1 = AD_(pr1, SQ_(p##17)); pr1 = AD_(pr1, SQ_(p##25)); pr1 = AD_(pr1, SQ_(p##33)); pr1 = AD_(pr1, SQ_(p##41)); pr1 = AD_(pr1, SQ_(p##49)); pr1 = AD_(pr1, SQ_(p##57)); \
  float pr2 = SQ_(p##2);  pr2 = AD_(pr2, SQ_(p##10)); pr2 = AD_(pr2, SQ_(p##18)); pr2 = AD_(pr2, SQ_(p##26)); pr2 = AD_(pr2, SQ_(p##34)); pr2 = AD_(pr2, SQ_(p##42)); pr2 = AD_(pr2, SQ_(p##50)); pr2 = AD_(pr2, SQ_(p##58)); \
  float pr3 = SQ_(p##3);  pr3 = AD_(pr3, SQ_(p##11)); pr3 = AD_(pr3, SQ_(p##19)); pr3 = AD_(pr3, SQ_(p##27)); pr3 = AD_(pr3, SQ_(p##35)); pr3 = AD_(pr3, SQ_(p##43)); pr3 = AD_(pr3, SQ_(p##51)); pr3 = AD_(pr3, SQ_(p##59)); \
  float pr4 = SQ_(p##4);  pr4 = AD_(pr4, SQ_(p##12)); pr4 = AD_(pr4, SQ_(p##20)); pr4 = AD_(pr4, SQ_(p##28)); pr4 = AD_(pr4, SQ_(p##36)); pr4 = AD_(pr4, SQ_(p##44)); pr4 = AD_(pr4, SQ_(p##52)); pr4 = AD_(pr4, SQ_(p##60)); \
  float pr5 = SQ_(p##5);  pr5 = AD_(pr5, SQ_(p##13)); pr5 = AD_(pr5, SQ_(p##21)); pr5 = AD_(pr5, SQ_(p##29)); pr5 = AD_(pr5, SQ_(p##37)); pr5 = AD_(pr5, SQ_(p##45)); pr5 = AD_(pr5, SQ_(p##53)); pr5 = AD_(pr5, SQ_(p##61)); \
  float pr6 = SQ_(p##6);  pr6 = AD_(pr6, SQ_(p##14)); pr6 = AD_(pr6, SQ_(p##22)); pr6 = AD_(pr6, SQ_(p##30)); pr6 = AD_(pr6, SQ_(p##38)); pr6 = AD_(pr6, SQ_(p##46)); pr6 = AD_(pr6, SQ_(p##54)); pr6 = AD_(pr6, SQ_(p##62)); \
  float pr7 = SQ_(p##7);  pr7 = AD_(pr7, SQ_(p##15)); pr7 = AD_(pr7, SQ_(p##23)); pr7 = AD_(pr7, SQ_(p##31)); pr7 = AD_(pr7, SQ_(p##39)); pr7 = AD_(pr7, SQ_(p##47)); pr7 = AD_(pr7, SQ_(p##55)); pr7 = AD_(pr7, SQ_(p##63)); \
  float dst = AD_(AD_(AD_(pr0, pr1), AD_(pr2, pr3)), AD_(AD_(pr4, pr5), AD_(pr6, pr7)));

// One thread per row; blockIdx.y = 256-code segment. z row staged in LDS
// column-major (conflict-free ds_read_b128 with imm offsets). Codebook read
// per-lane via forced-VGPR pointer -> global_load_dwordx4, vmcnt-pipelined.
// 8 codes per group, one serial FMA chain per code (sgemm order), 8-way ILP.
__global__ __launch_bounds__(256, 2)
void vq_dist_kernel(const float* __restrict__ z,
                    const float* __restrict__ cb,
                    float2* __restrict__ pairs) {
    const int tid = threadIdx.x;
    const int row = blockIdx.x * 256 + tid;           // 0..65535
    const int seg = blockIdx.y;                       // 0..3 (uniform)
    const int c0 = seg * CODES_PER_SEG;
    const int b = row >> 13;                          // uniform per block
    const int t = row & (T_DIM - 1);

    __shared__ float wsqs[CODES_PER_SEG];             // 1 KiB
    __shared__ float4 zl[16][256];                    // 64 KiB, [kchunk][tid]

    // --- per-block ||w||^2 for this segment's 256 codes (numpy op order) ---
    {
        const float* wp = cb + ((size_t)(c0 + tid) << 6);
#define LOADW(k) float w##k = wp[k];
        R64(LOADW)
#undef LOADW
        PAIRWISE64(w, s)
        wsqs[tid] = s;
    }

    // --- z row -> zsq (exact pairwise order) + LDS column-major staging ---
    // z[b, d, t]: stride T_DIM along d; lanes t-consecutive -> coalesced.
    const float* zp = z + (size_t)b * (D_DIM * T_DIM) + t;
#define LOADZ(k) float z##k = zp[(size_t)k * T_DIM];
    R64(LOADZ)
#undef LOADZ
    PAIRWISE64(z, zsq)
    zl[ 0][tid] = make_float4(z0,  z1,  z2,  z3);
    zl[ 1][tid] = make_float4(z4,  z5,  z6,  z7);
    zl[ 2][tid] = make_float4(z8,  z9,  z10, z11);
    zl[ 3][tid] = make_float4(z12, z13, z14, z15);
    zl[ 4][tid] = make_float4(z16, z17, z18, z19);
    zl[ 5][tid] = make_float4(z20, z21, z22, z23);
    zl[ 6][tid] = make_float4(z24, z25, z26, z27);
    zl[ 7][tid] = make_float4(z28, z29, z30, z31);
    zl[ 8][tid] = make_float4(z32, z33, z34, z35);
    zl[ 9][tid] = make_float4(z36, z37, z38, z39);
    zl[10][tid] = make_float4(z40, z41, z42, z43);
    zl[11][tid] = make_float4(z44, z45, z46, z47);
    zl[12][tid] = make_float4(z48, z49, z50, z51);
    zl[13][tid] = make_float4(z52, z53, z54, z55);
    zl[14][tid] = make_float4(z56, z57, z58, z59);
    zl[15][tid] = make_float4(z60, z61, z62, z63);
    __syncthreads();

    // Forced-VGPR codebook base: breaks uniformity proof -> per-lane
    // global_load_dwordx4 on the deeply-pipelined VMEM path (vmcnt),
    // instead of SGPR-chunked s_loads gated by lgkmcnt.
    const float4* wbase = (const float4*)(cb + ((size_t)c0 << 6));
    asm volatile("" : "+v"(wbase));

    float bestd = 3.4e38f;
    int besti = 0;
#pragma unroll 1
    for (int cc = 0; cc < CODES_PER_SEG; cc += 8) {
        const float4* wp4 = wbase + (cc << 4);  // cc*64 floats = cc*16 float4
        float a0 = 0.f, a1 = 0.f, a2 = 0.f, a3 = 0.f;
        float a4 = 0.f, a5 = 0.f, a6 = 0.f, a7 = 0.f;
#pragma unroll
        for (int kk = 0; kk < 16; ++kk) {
            const float4 zk = zl[kk][tid];    // ds_read_b128, conflict-free
            const float4 wv0 = wp4[  0 + kk]; // global_load_dwordx4, imm offs
            const float4 wv1 = wp4[ 16 + kk];
            const float4 wv2 = wp4[ 32 + kk];
            const float4 wv3 = wp4[ 48 + kk];
            const float4 wv4 = wp4[ 64 + kk];
            const float4 wv5 = wp4[ 80 + kk];
            const float4 wv6 = wp4[ 96 + kk];
            const float4 wv7 = wp4[112 + kk];
            // one serial chain per code, k ascending (bit-exact sgemm order)
#define CHAIN(n, wv) \
            a##n = fmaf(zk.x, wv.x, a##n); \
            a##n = fmaf(zk.y, wv.y, a##n); \
            a##n = fmaf(zk.z, wv.z, a##n); \
            a##n = fmaf(zk.w, wv.w, a##n);
            CHAIN(0, wv0) CHAIN(1, wv1) CHAIN(2, wv2) CHAIN(3, wv3)
            CHAIN(4, wv4) CHAIN(5, wv5) CHAIN(6, wv6) CHAIN(7, wv7)
#undef CHAIN
        }
        const float4 wqA = *(const float4*)(&wsqs[cc]);
        const float4 wqB = *(const float4*)(&wsqs[cc + 4]);
        // d = (zsq - 2*dot) + wsq, each op individually rounded; codes
        // checked in ascending order with strict < => first-min semantics.
        float d0 = __fadd_rn(__fsub_rn(zsq, __fmul_rn(2.0f, a0)), wqA.x);
        float d1 = __fadd_rn(__fsub_rn(zsq, __fmul_rn(2.0f, a1)), wqA.y);
        float d2 = __fadd_rn(__fsub_rn(zsq, __fmul_rn(2.0f, a2)), wqA.z);
        float d3 = __fadd_rn(__fsub_rn(zsq, __fmul_rn(2.0f, a3)), wqA.w);
        float d4 = __fadd_rn(__fsub_rn(zsq, __fmul_rn(2.0f, a4)), wqB.x);
        float d5 = __fadd_rn(__fsub_rn(zsq, __fmul_rn(2.0f, a5)), wqB.y);
        float d6 = __fadd_rn(__fsub_rn(zsq, __fmul_rn(2.0f, a6)), wqB.z);
        float d7 = __fadd_rn(__fsub_rn(zsq, __fmul_rn(2.0f, a7)), wqB.w);
        if (d0 < bestd) { bestd = d0; besti = c0 + cc + 0; }
        if (d1 < bestd) { bestd = d1; besti = c0 + cc + 1; }
        if (d2 < bestd) { bestd = d2; besti = c0 + cc + 2; }
        if (d3 < bestd) { bestd = d3; besti = c0 + cc + 3; }
        if (d4 < bestd) { bestd = d4; besti = c0 + cc + 4; }
        if (d5 < bestd) { bestd = d5; besti = c0 + cc + 5; }
        if (d6 < bestd) { bestd = d6; besti = c0 + cc + 6; }
        if (d7 < bestd) { bestd = d7; besti = c0 + cc + 7; }
    }
    pairs[seg * NROWS + row] = make_float2(bestd, (float)besti);
}

__global__ void vq_argmin_kernel(const float2* __restrict__ pairs,
                                 float* __restrict__ codes) {
    int row = blockIdx.x * blockDim.x + threadIdx.x;
    float2 best = pairs[row];
#pragma unroll
    for (int s = 1; s < SEGS; ++s) {
        float2 p = pairs[s * NROWS + row];
        if (p.x < best.x) best = p;  // ascending seg order, strict <
    }
    codes[row] = best.y;
}

// One float4 (4 consecutive t) per thread; per-block double partial to ws
// (no global atomics -> deterministic, no serialization).
__global__ void vq_epilogue_kernel(const float* __restrict__ z,
                                   const float* __restrict__ cb,
                                   const float* __restrict__ codes,
                                   float* __restrict__ out,
                                   double* __restrict__ partials) {
    const int q = blockIdx.x * 256 + threadIdx.x;  // quad index, 0..1048575
    const int i = q << 2;                          // element index
    const int t = i & (T_DIM - 1);                 // multiple of 4
    const int bd = i >> 13;
    const int d = bd & (D_DIM - 1);                // uniform within a wave
    const int b = bd >> 6;
    const int row = (b << 13) | t;

    float4 cr = *(const float4*)(codes + row);     // 4 consecutive codes
    float4 zv = *(const float4*)(z + i);
    float w0 = cb[((int)cr.x << 6) + d];           // gathers, 256 KiB table
    float w1 = cb[((int)cr.y << 6) + d];
    float w2 = cb[((int)cr.z << 6) + d];
    float w3 = cb[((int)cr.w << 6) + d];

    float4 df = make_float4(w0 - zv.x, w1 - zv.y, w2 - zv.z, w3 - zv.w);
    float4 o = make_float4(zv.x + df.x, zv.y + df.y, zv.z + df.z, zv.w + df.w);
    *(float4*)(out + i) = o;                       // z + (z_q - z), ref order

    double v = (double)df.x * df.x + (double)df.y * df.y +
               (double)df.z * df.z + (double)df.w * df.w;
#pragma unroll
    for (int o2 = 32; o2 > 0; o2 >>= 1) v += __shfl_down(v, o2, 64);

    __shared__ double red[4];
    if ((threadIdx.x & 63) == 0) red[threadIdx.x >> 6] = v;
    __syncthreads();
    if (threadIdx.x == 0)
        partials[blockIdx.x] = ((red[0] + red[1]) + (red[2] + red[3]));
}

__global__ void vq_loss_kernel(const double* __restrict__ partials,
                               float* __restrict__ out_loss) {
    double s = 0.0;
    for (int i = threadIdx.x; i < EPI_BLOCKS; i += 256) s += partials[i];
#pragma unroll
    for (int o = 32; o > 0; o >>= 1) s += __shfl_down(s, o, 64);
    __shared__ double red[4];
    if ((threadIdx.x & 63) == 0) red[threadIdx.x >> 6] = s;
    __syncthreads();
    if (threadIdx.x == 0) {
        double tot = (red[0] + red[1]) + (red[2] + red[3]);
        // vq_loss = codebook_loss + 0.25*commitment_loss = 1.25*mean(diff^2)
        out_loss[0] = (float)(1.25 * tot / (double)NELEM);
    }
}

extern "C" void kernel_launch(void* const* d_in, const int* in_sizes, int n_in,
                              void* d_out, int out_size, void* d_ws, size_t ws_size,
                              hipStream_t stream) {
    const float* z  = (const float*)d_in[0];   // 4194304
    const float* cb = (const float*)d_in[1];   // 65536

    float* out      = (float*)d_out;
    float* out_loss = out + NELEM;             // index 4194304
    float* codes    = out + NELEM + 1;         // 65536 floats

    char* ws    = (char*)d_ws;
    double* partials = (double*)(ws);                  // 32 KiB (4096 doubles)
    float2* pairs = (float2*)(ws + 32768);             // 2 MiB

    dim3 grid1(NROWS / 256, SEGS);
    vq_dist_kernel<<<grid1, 256, 0, stream>>>(z, cb, pairs);

    vq_argmin_kernel<<<NROWS / 256, 256, 0, stream>>>(pairs, codes);

    vq_epilogue_kernel<<<EPI_BLOCKS, 256, 0, stream>>>(z, cb, codes, out, partials);

    vq_loss_kernel<<<1, 256, 0, stream>>>(partials, out_loss);
}

// Round 7
// 275.948 us; speedup vs baseline: 2.0329x; 2.0329x over previous
//
#include <hip/hip_runtime.h>

// VectorQuantizer: z (8,64,8192) f32, codebook (1024,64) f32
// Outputs (concatenated f32): z_q_st [4194304], vq_loss [1], codes [65536]
//
// codes must match numpy fp32 argmin BIT-EXACTLY -> replicate numpy op order:
//   zsq/wsq: pairwise_sum n=64 (8 serial column accumulators, rounded squares)
//   dot:     single serial FMA chain over k ascending (BLAS sgemm order)
//   dist:    fl(fl(zsq - fl(2*dot)) + wsq), argmin = first occurrence of min.
//
// Evidence ledger:
//   R6-R8 (row-per-thread, w via s_load, z regs/AGPR): dist 190us, invariant
//     under pins & launch_bounds. R9 (z via LDS): STILL 190us. R11 (w via
//     per-lane VMEM): 500us -- uniform-address vector loads amplify 64x
//     through L1 (1KB served per 16B needed). VMEM path falsified.
//   Diagnosis: DS and SMEM share lgkmcnt and complete OOO relative to each
//     other -> loops mixing ds_read (z/wsqs) with s_load (w) force
//     lgkmcnt(0) FULL DRAINS -> every w batch serializes ~250cy L2 latency;
//     ~2.6 waves/SIMD can't cover it. Explains 190us = 3.1x FMA floor and
//     occupancy-insensitivity. AGPR "tax" was a red herring (gfx950 VALU
//     reads AGPRs directly -- why regalloc AGPR-homes at any budget).
// R12 (this round): TRANSPOSE the work -- lanes own CODES, not rows.
//   Each lane holds its 2 codes' w (32 float4 regs, loaded ONCE). Wave
//   iterates rows; z is wave-uniform -> LDS BROADCAST reads (16B/instr,
//   conflict-free by definition; NOT R11's per-lane 1KB). Inner loop is
//   pure-DS lgkm (in-order, counted waits pipeline) + FMA. Per-row argmin:
//   fminf butterfly + ballot/ffs first-min. 4 waves x 128 codes = 512
//   codes/block; blockIdx.y in {0,1}. Serial k-ascending chain per code
//   unchanged -> bit-exact.
//   Predict: dist 190 -> 70-105us; total -> 150-185us; LDS 73KB; Occ ~25%;
//   VGPR 160-200; bank-conflict ~0.
//   Falsifier: dist >=150us -> broadcast b128 expensive -> 4 codes/lane.

#define T_DIM 8192
#define D_DIM 64
#define C_DIM 1024
#define B_DIM 8
#define NROWS (B_DIM * T_DIM)           // 65536 vectors
#define NELEM (B_DIM * D_DIM * T_DIM)   // 4194304 elements
#define SEGS 2                          // blockIdx.y segments (512 codes each)
#define EPI_BLOCKS (NELEM / 4 / 256)    // 4096 blocks, 1 float4/thread

#define R64(M) M(0) M(1) M(2) M(3) M(4) M(5) M(6) M(7) \
  M(8) M(9) M(10) M(11) M(12) M(13) M(14) M(15) \
  M(16) M(17) M(18) M(19) M(20) M(21) M(22) M(23) \
  M(24) M(25) M(26) M(27) M(28) M(29) M(30) M(31) \
  M(32) M(33) M(34) M(35) M(36) M(37) M(38) M(39) \
  M(40) M(41) M(42) M(43) M(44) M(45) M(46) M(47) \
  M(48) M(49) M(50) M(51) M(52) M(53) M(54) M(55) \
  M(56) M(57) M(58) M(59) M(60) M(61) M(62) M(63)

#define SQ_(x) __fmul_rn(x, x)
#define AD_(a, b) __fadd_rn(a, b)

// numpy pairwise_sum of 64 pre-rounded squares of scalars p0..p63 -> dst.
#define PAIRWISE64(p, dst) \
  float pr0 = SQ_(p##0);  pr0 = AD_(pr0, SQ_(p##8));  pr0 = AD_(pr0, SQ_(p##16)); pr0 = AD_(pr0, SQ_(p##24)); pr0 = AD_(pr0, SQ_(p##32)); pr0 = AD_(pr0, SQ_(p##40)); pr0 = AD_(pr0, SQ_(p##48)); pr0 = AD_(pr0, SQ_(p##56)); \
  float pr1 = SQ_(p##1);  pr1 = AD_(pr1, SQ_(p##9));  pr1 = AD_(pr1, SQ_(p##17)); pr1 = AD_(pr1, SQ_(p##25)); pr1 = AD_(pr1, SQ_(p##33)); pr1 = AD_(pr1, SQ_(p##41)); pr1 = AD_(pr1, SQ_(p##49)); pr1 = AD_(pr1, SQ_(p##57)); \
  float pr2 = SQ_(p##2);  pr2 = AD_(pr2, SQ_(p##10)); pr2 = AD_(pr2, SQ_(p##18)); pr2 = AD_(pr2, SQ_(p##26)); pr2 = AD_(pr2, SQ_(p##34)); pr2 = AD_(pr2, SQ_(p##42)); pr2 = AD_(pr2, SQ_(p##50)); pr2 = AD_(pr2, SQ_(p##58)); \
  float pr3 = SQ_(p##3);  pr3 = AD_(pr3, SQ_(p##11)); pr3 = AD_(pr3, SQ_(p##19)); pr3 = AD_(pr3, SQ_(p##27)); pr3 = AD_(pr3, SQ_(p##35)); pr3 = AD_(pr3, SQ_(p##43)); pr3 = AD_(pr3, SQ_(p##51)); pr3 = AD_(pr3, SQ_(p##59)); \
  float pr4 = SQ_(p##4);  pr4 = AD_(pr4, SQ_(p##12)); pr4 = AD_(pr4, SQ_(p##20)); pr4 = AD_(pr4, SQ_(p##28)); pr4 = AD_(pr4, SQ_(p##36)); pr4 = AD_(pr4, SQ_(p##44)); pr4 = AD_(pr4, SQ_(p##52)); pr4 = AD_(pr4, SQ_(p##60)); \
  float pr5 = SQ_(p##5);  pr5 = AD_(pr5, SQ_(p##13)); pr5 = AD_(pr5, SQ_(p##21)); pr5 = AD_(pr5, SQ_(p##29)); pr5 = AD_(pr5, SQ_(p##37)); pr5 = AD_(pr5, SQ_(p##45)); pr5 = AD_(pr5, SQ_(p##53)); pr5 = AD_(pr5, SQ_(p##61)); \
  float pr6 = SQ_(p##6);  pr6 = AD_(pr6, SQ_(p##14)); pr6 = AD_(pr6, SQ_(p##22)); pr6 = AD_(pr6, SQ_(p##30)); pr6 = AD_(pr6, SQ_(p##38)); pr6 = AD_(pr6, SQ_(p##46)); pr6 = AD_(pr6, SQ_(p##54)); pr6 = AD_(pr6, SQ_(p##62)); \
  float pr7 = SQ_(p##7);  pr7 = AD_(pr7, SQ_(p##15)); pr7 = AD_(pr7, SQ_(p##23)); pr7 = AD_(pr7, SQ_(p##31)); pr7 = AD_(pr7, SQ_(p##39)); pr7 = AD_(pr7, SQ_(p##47)); pr7 = AD_(pr7, SQ_(p##55)); pr7 = AD_(pr7, SQ_(p##63)); \
  float dst = AD_(AD_(AD_(pr0, pr1), AD_(pr2, pr3)), AD_(AD_(pr4, pr5), AD_(pr6, pr7)));

// Same pairwise order, but sourced from a float4[16] register array.
// Column j accumulates elems j, j+8, ..., j+56: elem(i) = arr[i>>2].{comp i&3}
// j=0..3 -> even chunks comp x/y/z/w; j=4..7 -> odd chunks comp x/y/z/w.
#define WSQ_OF(arr, dst) float dst; { \
  float c0 = SQ_(arr[0].x); c0=AD_(c0,SQ_(arr[2].x)); c0=AD_(c0,SQ_(arr[4].x)); c0=AD_(c0,SQ_(arr[6].x)); c0=AD_(c0,SQ_(arr[8].x)); c0=AD_(c0,SQ_(arr[10].x)); c0=AD_(c0,SQ_(arr[12].x)); c0=AD_(c0,SQ_(arr[14].x)); \
  float c1 = SQ_(arr[0].y); c1=AD_(c1,SQ_(arr[2].y)); c1=AD_(c1,SQ_(arr[4].y)); c1=AD_(c1,SQ_(arr[6].y)); c1=AD_(c1,SQ_(arr[8].y)); c1=AD_(c1,SQ_(arr[10].y)); c1=AD_(c1,SQ_(arr[12].y)); c1=AD_(c1,SQ_(arr[14].y)); \
  float c2 = SQ_(arr[0].z); c2=AD_(c2,SQ_(arr[2].z)); c2=AD_(c2,SQ_(arr[4].z)); c2=AD_(c2,SQ_(arr[6].z)); c2=AD_(c2,SQ_(arr[8].z)); c2=AD_(c2,SQ_(arr[10].z)); c2=AD_(c2,SQ_(arr[12].z)); c2=AD_(c2,SQ_(arr[14].z)); \
  float c3 = SQ_(arr[0].w); c3=AD_(c3,SQ_(arr[2].w)); c3=AD_(c3,SQ_(arr[4].w)); c3=AD_(c3,SQ_(arr[6].w)); c3=AD_(c3,SQ_(arr[8].w)); c3=AD_(c3,SQ_(arr[10].w)); c3=AD_(c3,SQ_(arr[12].w)); c3=AD_(c3,SQ_(arr[14].w)); \
  float c4 = SQ_(arr[1].x); c4=AD_(c4,SQ_(arr[3].x)); c4=AD_(c4,SQ_(arr[5].x)); c4=AD_(c4,SQ_(arr[7].x)); c4=AD_(c4,SQ_(arr[9].x)); c4=AD_(c4,SQ_(arr[11].x)); c4=AD_(c4,SQ_(arr[13].x)); c4=AD_(c4,SQ_(arr[15].x)); \
  float c5 = SQ_(arr[1].y); c5=AD_(c5,SQ_(arr[3].y)); c5=AD_(c5,SQ_(arr[5].y)); c5=AD_(c5,SQ_(arr[7].y)); c5=AD_(c5,SQ_(arr[9].y)); c5=AD_(c5,SQ_(arr[11].y)); c5=AD_(c5,SQ_(arr[13].y)); c5=AD_(c5,SQ_(arr[15].y)); \
  float c6 = SQ_(arr[1].z); c6=AD_(c6,SQ_(arr[3].z)); c6=AD_(c6,SQ_(arr[5].z)); c6=AD_(c6,SQ_(arr[7].z)); c6=AD_(c6,SQ_(arr[9].z)); c6=AD_(c6,SQ_(arr[11].z)); c6=AD_(c6,SQ_(arr[13].z)); c6=AD_(c6,SQ_(arr[15].z)); \
  float c7 = SQ_(arr[1].w); c7=AD_(c7,SQ_(arr[3].w)); c7=AD_(c7,SQ_(arr[5].w)); c7=AD_(c7,SQ_(arr[7].w)); c7=AD_(c7,SQ_(arr[9].w)); c7=AD_(c7,SQ_(arr[11].w)); c7=AD_(c7,SQ_(arr[13].w)); c7=AD_(c7,SQ_(arr[15].w)); \
  dst = AD_(AD_(AD_(c0, c1), AD_(c2, c3)), AD_(AD_(c4, c5), AD_(c6, c7))); }

// Transpose layout: block = 256 threads = 4 waves; each wave owns 128 codes
// (lane -> codes cbase+lane and cbase+64+lane, w in registers); all waves
// iterate the block's 256-row z tile from LDS via uniform-address BROADCAST
// reads. Per row: 128 serial-k FMA chains (2/lane), dist, fminf butterfly,
// ballot first-min. Pure-DS lgkm in the loop -> counted waits, pipelined.
__global__ __launch_bounds__(256, 2)
void vq_dist_kernel(const float* __restrict__ z,
                    const float* __restrict__ cb,
                    float2* __restrict__ pairs) {
    const int tid  = threadIdx.x;
    const int wid  = tid >> 6;                        // 0..3
    const int lane = tid & 63;
    const int seg  = blockIdx.y;                      // 0..1
    const int row0 = blockIdx.x * 256;                // tile base (same b)
    const int b    = row0 >> 13;                      // 8192 % 256 == 0
    const int t0   = row0 & (T_DIM - 1);

    __shared__ float4 zl[16][256];                    // 64 KiB  [kchunk][row]
    __shared__ float  zsql[256];                      // 1 KiB
    __shared__ float2 res[4][256];                    // 8 KiB   [wave][row]

    // --- stage z tile: thread handles row row0+tid (coalesced d-strided) ---
    {
        const float* zp = z + (size_t)b * (D_DIM * T_DIM) + (t0 + tid);
#define LOADZ(k) float z##k = zp[(size_t)k * T_DIM];
        R64(LOADZ)
#undef LOADZ
        PAIRWISE64(z, zsq)
        zsql[tid] = zsq;
        zl[ 0][tid] = make_float4(z0,  z1,  z2,  z3);
        zl[ 1][tid] = make_float4(z4,  z5,  z6,  z7);
        zl[ 2][tid] = make_float4(z8,  z9,  z10, z11);
        zl[ 3][tid] = make_float4(z12, z13, z14, z15);
        zl[ 4][tid] = make_float4(z16, z17, z18, z19);
        zl[ 5][tid] = make_float4(z20, z21, z22, z23);
        zl[ 6][tid] = make_float4(z24, z25, z26, z27);
        zl[ 7][tid] = make_float4(z28, z29, z30, z31);
        zl[ 8][tid] = make_float4(z32, z33, z34, z35);
        zl[ 9][tid] = make_float4(z36, z37, z38, z39);
        zl[10][tid] = make_float4(z40, z41, z42, z43);
        zl[11][tid] = make_float4(z44, z45, z46, z47);
        zl[12][tid] = make_float4(z48, z49, z50, z51);
        zl[13][tid] = make_float4(z52, z53, z54, z55);
        zl[14][tid] = make_float4(z56, z57, z58, z59);
        zl[15][tid] = make_float4(z60, z61, z62, z63);
    }

    // --- my two codes' w into registers (one-time; 32 x float4) ---
    const int cbase = seg * 512 + wid * 128;          // wave's code base
    const int cA = cbase + lane;
    const int cB = cA + 64;
    float4 wa[16], wb[16];
    {
        const float4* wpa = (const float4*)(cb + ((size_t)cA << 6));
        const float4* wpb = (const float4*)(cb + ((size_t)cB << 6));
#pragma unroll
        for (int kk = 0; kk < 16; ++kk) { wa[kk] = wpa[kk]; wb[kk] = wpb[kk]; }
    }
    WSQ_OF(wa, wsqA)
    WSQ_OF(wb, wsqB)
    __syncthreads();

    // --- row loop: broadcast z, per-lane serial chains, per-row argmin ---
#pragma unroll 2
    for (int r = 0; r < 256; ++r) {
        float a = 0.f, a2 = 0.f;
#pragma unroll
        for (int kk = 0; kk < 16; ++kk) {
            const float4 zc = zl[kk][r];   // uniform addr -> broadcast read
            a  = fmaf(zc.x, wa[kk].x, a);
            a  = fmaf(zc.y, wa[kk].y, a);
            a  = fmaf(zc.z, wa[kk].z, a);
            a  = fmaf(zc.w, wa[kk].w, a);
            a2 = fmaf(zc.x, wb[kk].x, a2);
            a2 = fmaf(zc.y, wb[kk].y, a2);
            a2 = fmaf(zc.z, wb[kk].z, a2);
            a2 = fmaf(zc.w, wb[kk].w, a2);
        }
        const float zr = zsql[r];          // broadcast
        // d = (zsq - 2*dot) + wsq, each op individually rounded
        const float dA = __fadd_rn(__fsub_rn(zr, __fmul_rn(2.0f, a)),  wsqA);
        const float dB = __fadd_rn(__fsub_rn(zr, __fmul_rn(2.0f, a2)), wsqB);
        // pair pre-min: keep A on tie (cA < cB => first occurrence)
        const bool tookB = (dB < dA);
        const float d = tookB ? dB : dA;
        // wave min (value only)
        float m = d;
#pragma unroll
        for (int off = 32; off > 0; off >>= 1)
            m = fminf(m, __shfl_xor(m, off, 64));
        // first-min index: all A-codes < all B-codes; within a class,
        // lane order == code order -> lowest set lane wins.
        const unsigned long long mA = __ballot((!tookB) && (d == m));
        const unsigned long long mB = __ballot(tookB && (d == m));
        int code;
        if (mA) code = cbase + (__ffsll((long long)mA) - 1);
        else    code = cbase + 64 + (__ffsll((long long)mB) - 1);
        if (lane == 0) res[wid][r] = make_float2(m, (float)code);
    }
    __syncthreads();

    // --- combine the block's 4 waves (ascending wid == ascending codes) ---
    {
        float2 best = res[0][tid];
#pragma unroll
        for (int w = 1; w < 4; ++w) {
            const float2 p = res[w][tid];
            if (p.x < best.x) best = p;   // strict < keeps lower codes
        }
        pairs[seg * NROWS + row0 + tid] = best;
    }
}

__global__ void vq_argmin_kernel(const float2* __restrict__ pairs,
                                 float* __restrict__ codes) {
    int row = blockIdx.x * blockDim.x + threadIdx.x;
    float2 best = pairs[row];
#pragma unroll
    for (int s = 1; s < SEGS; ++s) {
        float2 p = pairs[s * NROWS + row];
        if (p.x < best.x) best = p;  // ascending seg order, strict <
    }
    codes[row] = best.y;
}

// One float4 (4 consecutive t) per thread; per-block double partial to ws
// (no global atomics -> deterministic, no serialization).
__global__ void vq_epilogue_kernel(const float* __restrict__ z,
                                   const float* __restrict__ cb,
                                   const float* __restrict__ codes,
                                   float* __restrict__ out,
                                   double* __restrict__ partials) {
    const int q = blockIdx.x * 256 + threadIdx.x;  // quad index, 0..1048575
    const int i = q << 2;                          // element index
    const int t = i & (T_DIM - 1);                 // multiple of 4
    const int bd = i >> 13;
    const int d = bd & (D_DIM - 1);                // uniform within a wave
    const int b = bd >> 6;
    const int row = (b << 13) | t;

    float4 cr = *(const float4*)(codes + row);     // 4 consecutive codes
    float4 zv = *(const float4*)(z + i);
    float w0 = cb[((int)cr.x << 6) + d];           // gathers, 256 KiB table
    float w1 = cb[((int)cr.y << 6) + d];
    float w2 = cb[((int)cr.z << 6) + d];
    float w3 = cb[((int)cr.w << 6) + d];

    float4 df = make_float4(w0 - zv.x, w1 - zv.y, w2 - zv.z, w3 - zv.w);
    float4 o = make_float4(zv.x + df.x, zv.y + df.y, zv.z + df.z, zv.w + df.w);
    *(float4*)(out + i) = o;                       // z + (z_q - z), ref order

    double v = (double)df.x * df.x + (double)df.y * df.y +
               (double)df.z * df.z + (double)df.w * df.w;
#pragma unroll
    for (int o2 = 32; o2 > 0; o2 >>= 1) v += __shfl_down(v, o2, 64);

    __shared__ double red[4];
    if ((threadIdx.x & 63) == 0) red[threadIdx.x >> 6] = v;
    __syncthreads();
    if (threadIdx.x == 0)
        partials[blockIdx.x] = ((red[0] + red[1]) + (red[2] + red[3]));
}

__global__ void vq_loss_kernel(const double* __restrict__ partials,
                               float* __restrict__ out_loss) {
    double s = 0.0;
    for (int i = threadIdx.x; i < EPI_BLOCKS; i += 256) s += partials[i];
#pragma unroll
    for (int o = 32; o > 0; o >>= 1) s += __shfl_down(s, o, 64);
    __shared__ double red[4];
    if ((threadIdx.x & 63) == 0) red[threadIdx.x >> 6] = s;
    __syncthreads();
    if (threadIdx.x == 0) {
        double tot = (red[0] + red[1]) + (red[2] + red[3]);
        // vq_loss = codebook_loss + 0.25*commitment_loss = 1.25*mean(diff^2)
        out_loss[0] = (float)(1.25 * tot / (double)NELEM);
    }
}

extern "C" void kernel_launch(void* const* d_in, const int* in_sizes, int n_in,
                              void* d_out, int out_size, void* d_ws, size_t ws_size,
                              hipStream_t stream) {
    const float* z  = (const float*)d_in[0];   // 4194304
    const float* cb = (const float*)d_in[1];   // 65536

    float* out      = (float*)d_out;
    float* out_loss = out + NELEM;             // index 4194304
    float* codes    = out + NELEM + 1;         // 65536 floats

    char* ws    = (char*)d_ws;
    double* partials = (double*)(ws);                  // 32 KiB (4096 doubles)
    float2* pairs = (float2*)(ws + 32768);             // 1 MiB (2 segs)

    dim3 grid1(NROWS / 256, SEGS);
    vq_dist_kernel<<<grid1, 256, 0, stream>>>(z, cb, pairs);

    vq_argmin_kernel<<<NROWS / 256, 256, 0, stream>>>(pairs, codes);

    vq_epilogue_kernel<<<EPI_BLOCKS, 256, 0, stream>>>(z, cb, codes, out, partials);

    vq_loss_kernel<<<1, 256, 0, stream>>>(partials, out_loss);
}

// Round 8
// 241.063 us; speedup vs baseline: 2.3270x; 1.1447x over previous
//
#include <hip/hip_runtime.h>

// VectorQuantizer: z (8,64,8192) f32, codebook (1024,64) f32
// Outputs (concatenated f32): z_q_st [4194304], vq_loss [1], codes [65536]
//
// codes must match numpy fp32 argmin BIT-EXACTLY -> replicate numpy op order:
//   zsq/wsq: pairwise_sum n=64 (8 serial column accumulators, rounded squares)
//   dot:     single serial FMA chain over k ascending (BLAS sgemm order)
//   dist:    fl(fl(zsq - fl(2*dot)) + wsq), argmin = first occurrence of min.
//
// Evidence ledger:
//   R6-R9: row-per-thread with w via s_load: dist 190us invariant (SMEM/DS
//     lgkmcnt OOO full-drains serialize w batches). R11: w via per-lane VMEM:
//     500us (64x L1 amplification). R12 transpose (lanes own codes, w in
//     regs ONCE, z broadcast from LDS): dist 209us, VALUBusy 47%.
//   R12 diagnosis: w-traffic eliminated but the per-row wave argmin is a
//     serial dependency chain: 6 dependent ds_bpermute (~60-100cy each under
//     8-wave DS contention) + ballots ~= 400-600cy/row unhideable at 2
//     waves/SIMD. Swapped SMEM serialization for shuffle serialization.
// R13 (this round): BATCH 4 ROWS per iteration. The 4 reduction chains are
//   independent -> interleave them (4 bpermutes in flight) => per-row stall
//   /4. Also 8 independent FMA chains (vs 2) for VALU ILP. Per-(row,code)
//   FMA order untouched -> bit-exact. ~190 regs < 256 at (256,2).
//   Predict: dist 209 -> 130-160us; total -> 195-225; VALUBusy 60-75%.
//   Falsifier: dist >=190 -> DS-pipe THROUGHPUT bound (broadcast+shfl share
//   pipe) -> next: LDS-scan reduction replacing shfls entirely.

#define T_DIM 8192
#define D_DIM 64
#define C_DIM 1024
#define B_DIM 8
#define NROWS (B_DIM * T_DIM)           // 65536 vectors
#define NELEM (B_DIM * D_DIM * T_DIM)   // 4194304 elements
#define SEGS 2                          // blockIdx.y segments (512 codes each)
#define EPI_BLOCKS (NELEM / 4 / 256)    // 4096 blocks, 1 float4/thread

#define R64(M) M(0) M(1) M(2) M(3) M(4) M(5) M(6) M(7) \
  M(8) M(9) M(10) M(11) M(12) M(13) M(14) M(15) \
  M(16) M(17) M(18) M(19) M(20) M(21) M(22) M(23) \
  M(24) M(25) M(26) M(27) M(28) M(29) M(30) M(31) \
  M(32) M(33) M(34) M(35) M(36) M(37) M(38) M(39) \
  M(40) M(41) M(42) M(43) M(44) M(45) M(46) M(47) \
  M(48) M(49) M(50) M(51) M(52) M(53) M(54) M(55) \
  M(56) M(57) M(58) M(59) M(60) M(61) M(62) M(63)

#define SQ_(x) __fmul_rn(x, x)
#define AD_(a, b) __fadd_rn(a, b)

// numpy pairwise_sum of 64 pre-rounded squares of scalars p0..p63 -> dst.
#define PAIRWISE64(p, dst) \
  float pr0 = SQ_(p##0);  pr0 = AD_(pr0, SQ_(p##8));  pr0 = AD_(pr0, SQ_(p##16)); pr0 = AD_(pr0, SQ_(p##24)); pr0 = AD_(pr0, SQ_(p##32)); pr0 = AD_(pr0, SQ_(p##40)); pr0 = AD_(pr0, SQ_(p##48)); pr0 = AD_(pr0, SQ_(p##56)); \
  float pr1 = SQ_(p##1);  pr1 = AD_(pr1, SQ_(p##9));  pr1 = AD_(pr1, SQ_(p##17)); pr1 = AD_(pr1, SQ_(p##25)); pr1 = AD_(pr1, SQ_(p##33)); pr1 = AD_(pr1, SQ_(p##41)); pr1 = AD_(pr1, SQ_(p##49)); pr1 = AD_(pr1, SQ_(p##57)); \
  float pr2 = SQ_(p##2);  pr2 = AD_(pr2, SQ_(p##10)); pr2 = AD_(pr2, SQ_(p##18)); pr2 = AD_(pr2, SQ_(p##26)); pr2 = AD_(pr2, SQ_(p##34)); pr2 = AD_(pr2, SQ_(p##42)); pr2 = AD_(pr2, SQ_(p##50)); pr2 = AD_(pr2, SQ_(p##58)); \
  float pr3 = SQ_(p##3);  pr3 = AD_(pr3, SQ_(p##11)); pr3 = AD_(pr3, SQ_(p##19)); pr3 = AD_(pr3, SQ_(p##27)); pr3 = AD_(pr3, SQ_(p##35)); pr3 = AD_(pr3, SQ_(p##43)); pr3 = AD_(pr3, SQ_(p##51)); pr3 = AD_(pr3, SQ_(p##59)); \
  float pr4 = SQ_(p##4);  pr4 = AD_(pr4, SQ_(p##12)); pr4 = AD_(pr4, SQ_(p##20)); pr4 = AD_(pr4, SQ_(p##28)); pr4 = AD_(pr4, SQ_(p##36)); pr4 = AD_(pr4, SQ_(p##44)); pr4 = AD_(pr4, SQ_(p##52)); pr4 = AD_(pr4, SQ_(p##60)); \
  float pr5 = SQ_(p##5);  pr5 = AD_(pr5, SQ_(p##13)); pr5 = AD_(pr5, SQ_(p##21)); pr5 = AD_(pr5, SQ_(p##29)); pr5 = AD_(pr5, SQ_(p##37)); pr5 = AD_(pr5, SQ_(p##45)); pr5 = AD_(pr5, SQ_(p##53)); pr5 = AD_(pr5, SQ_(p##61)); \
  float pr6 = SQ_(p##6);  pr6 = AD_(pr6, SQ_(p##14)); pr6 = AD_(pr6, SQ_(p##22)); pr6 = AD_(pr6, SQ_(p##30)); pr6 = AD_(pr6, SQ_(p##38)); pr6 = AD_(pr6, SQ_(p##46)); pr6 = AD_(pr6, SQ_(p##54)); pr6 = AD_(pr6, SQ_(p##62)); \
  float pr7 = SQ_(p##7);  pr7 = AD_(pr7, SQ_(p##15)); pr7 = AD_(pr7, SQ_(p##23)); pr7 = AD_(pr7, SQ_(p##31)); pr7 = AD_(pr7, SQ_(p##39)); pr7 = AD_(pr7, SQ_(p##47)); pr7 = AD_(pr7, SQ_(p##55)); pr7 = AD_(pr7, SQ_(p##63)); \
  float dst = AD_(AD_(AD_(pr0, pr1), AD_(pr2, pr3)), AD_(AD_(pr4, pr5), AD_(pr6, pr7)));

// Same pairwise order, sourced from a float4[16] register array.
#define WSQ_OF(arr, dst) float dst; { \
  float c0 = SQ_(arr[0].x); c0=AD_(c0,SQ_(arr[2].x)); c0=AD_(c0,SQ_(arr[4].x)); c0=AD_(c0,SQ_(arr[6].x)); c0=AD_(c0,SQ_(arr[8].x)); c0=AD_(c0,SQ_(arr[10].x)); c0=AD_(c0,SQ_(arr[12].x)); c0=AD_(c0,SQ_(arr[14].x)); \
  float c1 = SQ_(arr[0].y); c1=AD_(c1,SQ_(arr[2].y)); c1=AD_(c1,SQ_(arr[4].y)); c1=AD_(c1,SQ_(arr[6].y)); c1=AD_(c1,SQ_(arr[8].y)); c1=AD_(c1,SQ_(arr[10].y)); c1=AD_(c1,SQ_(arr[12].y)); c1=AD_(c1,SQ_(arr[14].y)); \
  float c2 = SQ_(arr[0].z); c2=AD_(c2,SQ_(arr[2].z)); c2=AD_(c2,SQ_(arr[4].z)); c2=AD_(c2,SQ_(arr[6].z)); c2=AD_(c2,SQ_(arr[8].z)); c2=AD_(c2,SQ_(arr[10].z)); c2=AD_(c2,SQ_(arr[12].z)); c2=AD_(c2,SQ_(arr[14].z)); \
  float c3 = SQ_(arr[0].w); c3=AD_(c3,SQ_(arr[2].w)); c3=AD_(c3,SQ_(arr[4].w)); c3=AD_(c3,SQ_(arr[6].w)); c3=AD_(c3,SQ_(arr[8].w)); c3=AD_(c3,SQ_(arr[10].w)); c3=AD_(c3,SQ_(arr[12].w)); c3=AD_(c3,SQ_(arr[14].w)); \
  float c4 = SQ_(arr[1].x); c4=AD_(c4,SQ_(arr[3].x)); c4=AD_(c4,SQ_(arr[5].x)); c4=AD_(c4,SQ_(arr[7].x)); c4=AD_(c4,SQ_(arr[9].x)); c4=AD_(c4,SQ_(arr[11].x)); c4=AD_(c4,SQ_(arr[13].x)); c4=AD_(c4,SQ_(arr[15].x)); \
  float c5 = SQ_(arr[1].y); c5=AD_(c5,SQ_(arr[3].y)); c5=AD_(c5,SQ_(arr[5].y)); c5=AD_(c5,SQ_(arr[7].y)); c5=AD_(c5,SQ_(arr[9].y)); c5=AD_(c5,SQ_(arr[11].y)); c5=AD_(c5,SQ_(arr[13].y)); c5=AD_(c5,SQ_(arr[15].y)); \
  float c6 = SQ_(arr[1].z); c6=AD_(c6,SQ_(arr[3].z)); c6=AD_(c6,SQ_(arr[5].z)); c6=AD_(c6,SQ_(arr[7].z)); c6=AD_(c6,SQ_(arr[9].z)); c6=AD_(c6,SQ_(arr[11].z)); c6=AD_(c6,SQ_(arr[13].z)); c6=AD_(c6,SQ_(arr[15].z)); \
  float c7 = SQ_(arr[1].w); c7=AD_(c7,SQ_(arr[3].w)); c7=AD_(c7,SQ_(arr[5].w)); c7=AD_(c7,SQ_(arr[7].w)); c7=AD_(c7,SQ_(arr[9].w)); c7=AD_(c7,SQ_(arr[11].w)); c7=AD_(c7,SQ_(arr[13].w)); c7=AD_(c7,SQ_(arr[15].w)); \
  dst = AD_(AD_(AD_(c0, c1), AD_(c2, c3)), AD_(AD_(c4, c5), AD_(c6, c7))); }

// Transpose layout: block = 4 waves; each wave owns 128 codes (lane -> codes
// cbase+lane, cbase+64+lane; w in registers). Waves iterate the block's 256
// rows from LDS via broadcast reads, 4 ROWS PER ITERATION: 8 independent FMA
// chains, then 4 independent interleaved shfl-min chains (pipelined).
__global__ __launch_bounds__(256, 2)
void vq_dist_kernel(const float* __restrict__ z,
                    const float* __restrict__ cb,
                    float2* __restrict__ pairs) {
    const int tid  = threadIdx.x;
    const int wid  = tid >> 6;                        // 0..3
    const int lane = tid & 63;
    const int seg  = blockIdx.y;                      // 0..1
    const int row0 = blockIdx.x * 256;                // tile base (same b)
    const int b    = row0 >> 13;                      // 8192 % 256 == 0
    const int t0   = row0 & (T_DIM - 1);

    __shared__ float4 zl[16][256];                    // 64 KiB  [kchunk][row]
    __shared__ float  zsql[256];                      // 1 KiB
    __shared__ float2 res[4][256];                    // 8 KiB   [wave][row]

    // --- stage z tile: thread handles row row0+tid (coalesced d-strided) ---
    {
        const float* zp = z + (size_t)b * (D_DIM * T_DIM) + (t0 + tid);
#define LOADZ(k) float z##k = zp[(size_t)k * T_DIM];
        R64(LOADZ)
#undef LOADZ
        PAIRWISE64(z, zsq)
        zsql[tid] = zsq;
        zl[ 0][tid] = make_float4(z0,  z1,  z2,  z3);
        zl[ 1][tid] = make_float4(z4,  z5,  z6,  z7);
        zl[ 2][tid] = make_float4(z8,  z9,  z10, z11);
        zl[ 3][tid] = make_float4(z12, z13, z14, z15);
        zl[ 4][tid] = make_float4(z16, z17, z18, z19);
        zl[ 5][tid] = make_float4(z20, z21, z22, z23);
        zl[ 6][tid] = make_float4(z24, z25, z26, z27);
        zl[ 7][tid] = make_float4(z28, z29, z30, z31);
        zl[ 8][tid] = make_float4(z32, z33, z34, z35);
        zl[ 9][tid] = make_float4(z36, z37, z38, z39);
        zl[10][tid] = make_float4(z40, z41, z42, z43);
        zl[11][tid] = make_float4(z44, z45, z46, z47);
        zl[12][tid] = make_float4(z48, z49, z50, z51);
        zl[13][tid] = make_float4(z52, z53, z54, z55);
        zl[14][tid] = make_float4(z56, z57, z58, z59);
        zl[15][tid] = make_float4(z60, z61, z62, z63);
    }

    // --- my two codes' w into registers (one-time; 32 x float4) ---
    const int cbase = seg * 512 + wid * 128;          // wave's code base
    const int cA = cbase + lane;
    const int cB = cA + 64;
    float4 wa[16], wb[16];
    {
        const float4* wpa = (const float4*)(cb + ((size_t)cA << 6));
        const float4* wpb = (const float4*)(cb + ((size_t)cB << 6));
#pragma unroll
        for (int kk = 0; kk < 16; ++kk) { wa[kk] = wpa[kk]; wb[kk] = wpb[kk]; }
    }
    WSQ_OF(wa, wsqA)
    WSQ_OF(wb, wsqB)
    __syncthreads();

    // --- row loop, 4 rows/iter: broadcast z, 8 FMA chains, 4 interleaved
    //     shfl-min chains (latency pipelined), ballot first-min per row ---
#pragma unroll 1
    for (int r = 0; r < 256; r += 4) {
        float aA0 = 0.f, aA1 = 0.f, aA2 = 0.f, aA3 = 0.f;
        float aB0 = 0.f, aB1 = 0.f, aB2 = 0.f, aB3 = 0.f;
#pragma unroll
        for (int kk = 0; kk < 16; ++kk) {
            const float4 zc0 = zl[kk][r + 0];   // broadcast reads
            const float4 zc1 = zl[kk][r + 1];
            const float4 zc2 = zl[kk][r + 2];
            const float4 zc3 = zl[kk][r + 3];
            const float4 WA = wa[kk];
            const float4 WB = wb[kk];
            aA0 = fmaf(zc0.x, WA.x, aA0); aA0 = fmaf(zc0.y, WA.y, aA0);
            aA0 = fmaf(zc0.z, WA.z, aA0); aA0 = fmaf(zc0.w, WA.w, aA0);
            aB0 = fmaf(zc0.x, WB.x, aB0); aB0 = fmaf(zc0.y, WB.y, aB0);
            aB0 = fmaf(zc0.z, WB.z, aB0); aB0 = fmaf(zc0.w, WB.w, aB0);
            aA1 = fmaf(zc1.x, WA.x, aA1); aA1 = fmaf(zc1.y, WA.y, aA1);
            aA1 = fmaf(zc1.z, WA.z, aA1); aA1 = fmaf(zc1.w, WA.w, aA1);
            aB1 = fmaf(zc1.x, WB.x, aB1); aB1 = fmaf(zc1.y, WB.y, aB1);
            aB1 = fmaf(zc1.z, WB.z, aB1); aB1 = fmaf(zc1.w, WB.w, aB1);
            aA2 = fmaf(zc2.x, WA.x, aA2); aA2 = fmaf(zc2.y, WA.y, aA2);
            aA2 = fmaf(zc2.z, WA.z, aA2); aA2 = fmaf(zc2.w, WA.w, aA2);
            aB2 = fmaf(zc2.x, WB.x, aB2); aB2 = fmaf(zc2.y, WB.y, aB2);
            aB2 = fmaf(zc2.z, WB.z, aB2); aB2 = fmaf(zc2.w, WB.w, aB2);
            aA3 = fmaf(zc3.x, WA.x, aA3); aA3 = fmaf(zc3.y, WA.y, aA3);
            aA3 = fmaf(zc3.z, WA.z, aA3); aA3 = fmaf(zc3.w, WA.w, aA3);
            aB3 = fmaf(zc3.x, WB.x, aB3); aB3 = fmaf(zc3.y, WB.y, aB3);
            aB3 = fmaf(zc3.z, WB.z, aB3); aB3 = fmaf(zc3.w, WB.w, aB3);
        }
        const float zr0 = zsql[r + 0];
        const float zr1 = zsql[r + 1];
        const float zr2 = zsql[r + 2];
        const float zr3 = zsql[r + 3];
        // d = (zsq - 2*dot) + wsq, each op individually rounded
        const float dA0 = __fadd_rn(__fsub_rn(zr0, __fmul_rn(2.0f, aA0)), wsqA);
        const float dB0 = __fadd_rn(__fsub_rn(zr0, __fmul_rn(2.0f, aB0)), wsqB);
        const float dA1 = __fadd_rn(__fsub_rn(zr1, __fmul_rn(2.0f, aA1)), wsqA);
        const float dB1 = __fadd_rn(__fsub_rn(zr1, __fmul_rn(2.0f, aB1)), wsqB);
        const float dA2 = __fadd_rn(__fsub_rn(zr2, __fmul_rn(2.0f, aA2)), wsqA);
        const float dB2 = __fadd_rn(__fsub_rn(zr2, __fmul_rn(2.0f, aB2)), wsqB);
        const float dA3 = __fadd_rn(__fsub_rn(zr3, __fmul_rn(2.0f, aA3)), wsqA);
        const float dB3 = __fadd_rn(__fsub_rn(zr3, __fmul_rn(2.0f, aB3)), wsqB);
        // pair pre-min (A wins ties: lower code)
        const bool tB0 = (dB0 < dA0); const float d0 = tB0 ? dB0 : dA0;
        const bool tB1 = (dB1 < dA1); const float d1 = tB1 ? dB1 : dA1;
        const bool tB2 = (dB2 < dA2); const float d2 = tB2 ? dB2 : dA2;
        const bool tB3 = (dB3 < dA3); const float d3 = tB3 ? dB3 : dA3;
        // 4 independent wave-min chains, interleaved -> pipelined bpermutes
        float m0 = d0, m1 = d1, m2 = d2, m3 = d3;
#pragma unroll
        for (int off = 32; off > 0; off >>= 1) {
            m0 = fminf(m0, __shfl_xor(m0, off, 64));
            m1 = fminf(m1, __shfl_xor(m1, off, 64));
            m2 = fminf(m2, __shfl_xor(m2, off, 64));
            m3 = fminf(m3, __shfl_xor(m3, off, 64));
        }
        // first-min index per row (A-class before B-class; lane order = code
        // order within a class)
#define ARGMIN_J(mj, dj, tBj, outIdx) { \
        const unsigned long long mskA = __ballot((!tBj) && (dj == mj)); \
        const unsigned long long mskB = __ballot(tBj && (dj == mj)); \
        int code; \
        if (mskA) code = cbase + (__ffsll((long long)mskA) - 1); \
        else      code = cbase + 64 + (__ffsll((long long)mskB) - 1); \
        if (lane == 0) res[wid][outIdx] = make_float2(mj, (float)code); }
        ARGMIN_J(m0, d0, tB0, r + 0)
        ARGMIN_J(m1, d1, tB1, r + 1)
        ARGMIN_J(m2, d2, tB2, r + 2)
        ARGMIN_J(m3, d3, tB3, r + 3)
#undef ARGMIN_J
    }
    __syncthreads();

    // --- combine the block's 4 waves (ascending wid == ascending codes) ---
    {
        float2 best = res[0][tid];
#pragma unroll
        for (int w = 1; w < 4; ++w) {
            const float2 p = res[w][tid];
            if (p.x < best.x) best = p;   // strict < keeps lower codes
        }
        pairs[seg * NROWS + row0 + tid] = best;
    }
}

__global__ void vq_argmin_kernel(const float2* __restrict__ pairs,
                                 float* __restrict__ codes) {
    int row = blockIdx.x * blockDim.x + threadIdx.x;
    float2 best = pairs[row];
#pragma unroll
    for (int s = 1; s < SEGS; ++s) {
        float2 p = pairs[s * NROWS + row];
        if (p.x < best.x) best = p;  // ascending seg order, strict <
    }
    codes[row] = best.y;
}

// One float4 (4 consecutive t) per thread; per-block double partial to ws
// (no global atomics -> deterministic, no serialization).
__global__ void vq_epilogue_kernel(const float* __restrict__ z,
                                   const float* __restrict__ cb,
                                   const float* __restrict__ codes,
                                   float* __restrict__ out,
                                   double* __restrict__ partials) {
    const int q = blockIdx.x * 256 + threadIdx.x;  // quad index, 0..1048575
    const int i = q << 2;                          // element index
    const int t = i & (T_DIM - 1);                 // multiple of 4
    const int bd = i >> 13;
    const int d = bd & (D_DIM - 1);                // uniform within a wave
    const int b = bd >> 6;
    const int row = (b << 13) | t;

    float4 cr = *(const float4*)(codes + row);     // 4 consecutive codes
    float4 zv = *(const float4*)(z + i);
    float w0 = cb[((int)cr.x << 6) + d];           // gathers, 256 KiB table
    float w1 = cb[((int)cr.y << 6) + d];
    float w2 = cb[((int)cr.z << 6) + d];
    float w3 = cb[((int)cr.w << 6) + d];

    float4 df = make_float4(w0 - zv.x, w1 - zv.y, w2 - zv.z, w3 - zv.w);
    float4 o = make_float4(zv.x + df.x, zv.y + df.y, zv.z + df.z, zv.w + df.w);
    *(float4*)(out + i) = o;                       // z + (z_q - z), ref order

    double v = (double)df.x * df.x + (double)df.y * df.y +
               (double)df.z * df.z + (double)df.w * df.w;
#pragma unroll
    for (int o2 = 32; o2 > 0; o2 >>= 1) v += __shfl_down(v, o2, 64);

    __shared__ double red[4];
    if ((threadIdx.x & 63) == 0) red[threadIdx.x >> 6] = v;
    __syncthreads();
    if (threadIdx.x == 0)
        partials[blockIdx.x] = ((red[0] + red[1]) + (red[2] + red[3]));
}

__global__ void vq_loss_kernel(const double* __restrict__ partials,
                               float* __restrict__ out_loss) {
    double s = 0.0;
    for (int i = threadIdx.x; i < EPI_BLOCKS; i += 256) s += partials[i];
#pragma unroll
    for (int o = 32; o > 0; o >>= 1) s += __shfl_down(s, o, 64);
    __shared__ double red[4];
    if ((threadIdx.x & 63) == 0) red[threadIdx.x >> 6] = s;
    __syncthreads();
    if (threadIdx.x == 0) {
        double tot = (red[0] + red[1]) + (red[2] + red[3]);
        // vq_loss = codebook_loss + 0.25*commitment_loss = 1.25*mean(diff^2)
        out_loss[0] = (float)(1.25 * tot / (double)NELEM);
    }
}

extern "C" void kernel_launch(void* const* d_in, const int* in_sizes, int n_in,
                              void* d_out, int out_size, void* d_ws, size_t ws_size,
                              hipStream_t stream) {
    const float* z  = (const float*)d_in[0];   // 4194304
    const float* cb = (const float*)d_in[1];   // 65536

    float* out      = (float*)d_out;
    float* out_loss = out + NELEM;             // index 4194304
    float* codes    = out + NELEM + 1;         // 65536 floats

    char* ws    = (char*)d_ws;
    double* partials = (double*)(ws);                  // 32 KiB (4096 doubles)
    float2* pairs = (float2*)(ws + 32768);             // 1 MiB (2 segs)

    dim3 grid1(NROWS / 256, SEGS);
    vq_dist_kernel<<<grid1, 256, 0, stream>>>(z, cb, pairs);

    vq_argmin_kernel<<<NROWS / 256, 256, 0, stream>>>(pairs, codes);

    vq_epilogue_kernel<<<EPI_BLOCKS, 256, 0, stream>>>(z, cb, codes, out, partials);

    vq_loss_kernel<<<1, 256, 0, stream>>>(partials, out_loss);
}